// Round 3
// baseline (334.321 us; speedup 1.0000x reference)
//
#include <hip/hip_runtime.h>
#include <hip/hip_cooperative_groups.h>
#include <math.h>

namespace cg = cooperative_groups;

#define B_ 128
#define G_ 16
#define A_ 8732
#define C_ 21
#define THR_ 0.5f
#define NEG_POS_ 3
#define VAR0_ 0.1f
#define VAR1_ 0.2f

#define BA_    (B_ * A_)          // 1,117,696
#define GRID_  256                // one block per CU-half; full machine
#define CHA_   512                // anchors per chunk
#define NCH_   (BA_ / CHA_)       // 2183 chunks, exact (1117696 = 512*2183)
#define CV4_   (CHA_ * C_ / 4)    // 2688 float4 per chunk (43008 B)
#define NPT_   ((A_ + 511) / 512) // 18 aux values per thread in phase D

// ---------------------------------------------------------------------------
// Single cooperative kernel, grid = 256 x 512.
//  A (blocks 0-127): per-batch IoU matching (verified logic) -> match codes,
//                    npos. LDS-internal; only final codes hit global.
//  C (all blocks)  : loss over flat 512-anchor chunks, grid-strided;
//                    double-buffered LDS conf staging, loads for chunk k+1
//                    overlap compute of chunk k. Writes aux + block partials.
//  D (blocks 0-127): per-batch hard-negative mining (verified binary search).
//  E (block 0)     : final reduce -> out.
// grid.sync() between phases replaces 4 kernel boundaries.
// ---------------------------------------------------------------------------
__global__ __launch_bounds__(512) void k_all(
    const float* __restrict__ pred_off,   // B,A,4
    const float* __restrict__ pred_conf,  // B,A,C
    const float* __restrict__ tboxes,     // B,G,4 (point form)
    const int*   __restrict__ tlabels,    // B,G
    const float* __restrict__ anchors,    // A,4 (center form)
    int*         __restrict__ match,      // BA
    float*       __restrict__ aux,        // BA
    int*         __restrict__ npos_b,     // B
    float*       __restrict__ ploc_b,     // GRID_
    float*       __restrict__ pcls_b,     // GRID_
    float*       __restrict__ scls_b,     // B
    float*       __restrict__ out)        // 2
{
    cg::grid_group gridg = cg::this_grid();
    const int tid  = threadIdx.x;
    const int lane = tid & 63;
    const int w    = tid >> 6;            // 0..7
    const int bid  = blockIdx.x;

    __shared__ float         s_ov[A_];            // 34928 B (phase A only)
    __shared__ unsigned char s_gi[A_];            //  8732 B (phase A only)
    __shared__ float4        s_stage[2][CV4_];    // 86016 B (phase C)
    __shared__ float s_boxlds[G_ * 4];
    __shared__ int   s_lab[G_];
    __shared__ unsigned long long s_gb[8 * G_];
    __shared__ int   s_forced[G_];
    __shared__ int   s_cnt[8];
    __shared__ int   s_c[2][8];
    __shared__ float s_r0[8], s_r1[8], s_r3[8];
    __shared__ int   s_r2[8];

    // ================= Phase A: matching (blocks 0..127) =================
    if (bid < B_) {
        const int b = bid;
        if (tid < G_ * 4) s_boxlds[tid] = tboxes[b * G_ * 4 + tid];
        if (tid < G_)     s_lab[tid]    = tlabels[b * G_ + tid];
        __syncthreads();

        float bx0[G_], by0[G_], bx1[G_], by1[G_], bar[G_];
        #pragma unroll
        for (int g = 0; g < G_; ++g) {
            bx0[g] = s_boxlds[g * 4 + 0];
            by0[g] = s_boxlds[g * 4 + 1];
            bx1[g] = s_boxlds[g * 4 + 2];
            by1[g] = s_boxlds[g * 4 + 3];
            bar[g] = (bx1[g] - bx0[g]) * (by1[g] - by0[g]);
        }

        unsigned long long gb[G_];
        #pragma unroll
        for (int g = 0; g < G_; ++g) gb[g] = 0ull;

        for (int a = tid; a < A_; a += 512) {
            float4 an = ((const float4*)anchors)[a];
            float ax0 = an.x - an.z * 0.5f, ay0 = an.y - an.w * 0.5f;
            float ax1 = an.x + an.z * 0.5f, ay1 = an.y + an.w * 0.5f;
            float area_b = (ax1 - ax0) * (ay1 - ay0);
            float bov = -1.f; int bg = 0;
            #pragma unroll
            for (int g = 0; g < G_; ++g) {
                float tlx = fmaxf(bx0[g], ax0);
                float tly = fmaxf(by0[g], ay0);
                float brx = fminf(bx1[g], ax1);
                float bry = fminf(by1[g], ay1);
                float wdt = fmaxf(brx - tlx, 0.f);
                float hgt = fmaxf(bry - tly, 0.f);
                float inter = wdt * hgt;
                float iou = inter / (bar[g] + area_b - inter);
                if (iou > bov) { bov = iou; bg = g; }   // first g wins on ties
                unsigned long long pk =
                    ((unsigned long long)__float_as_uint(iou) << 32) |
                    (unsigned)(~(unsigned)a);           // max iou, min a on ties
                if (pk > gb[g]) gb[g] = pk;
            }
            s_ov[a] = bov;
            s_gi[a] = (unsigned char)bg;
        }

        #pragma unroll
        for (int g = 0; g < G_; ++g) {
            #pragma unroll
            for (int off = 32; off > 0; off >>= 1) {
                unsigned long long o = __shfl_down(gb[g], off);
                if (o > gb[g]) gb[g] = o;
            }
        }
        if (lane == 0) {
            #pragma unroll
            for (int g = 0; g < G_; ++g) s_gb[w * G_ + g] = gb[g];
        }
        __syncthreads();
        if (tid < G_) {
            unsigned long long m = 0ull;
            #pragma unroll
            for (int wv = 0; wv < 8; ++wv) {
                unsigned long long v = s_gb[wv * G_ + tid];
                if (v > m) m = v;
            }
            s_forced[tid] = (int)(~(unsigned)(m & 0xFFFFFFFFull));
        }
        __syncthreads();
        if (tid == 0) {
            for (int g = 0; g < G_; ++g) {      // ascending g, last write wins
                int a = s_forced[g];
                s_ov[a] = 1.0f;
                s_gi[a] = (unsigned char)g;
            }
        }
        __syncthreads();

        int cnt = 0;
        for (int a = tid; a < A_; a += 512) {
            float ov = s_ov[a];
            int g = s_gi[a];
            int conf = (ov < THR_) ? 0 : (s_lab[g] + 1);
            match[b * A_ + a] = conf | (g << 8);
            cnt += (conf > 0);
        }
        #pragma unroll
        for (int off = 32; off > 0; off >>= 1) cnt += __shfl_down(cnt, off);
        if (lane == 0) s_cnt[w] = cnt;
        __syncthreads();
        if (tid == 0) {
            int t = 0;
            #pragma unroll
            for (int wv = 0; wv < 8; ++wv) t += s_cnt[wv];
            npos_b[b] = t;
        }
    }
    gridg.sync();

    // ================= Phase C: loss (all blocks, grid-stride chunks) =====
    {
        float lloc = 0.f, pnll = 0.f;
        const float4* gbase = (const float4*)pred_conf;
        float4 r[6];
        int c = bid;

        // prologue: stage chunk bid into buf 0, prefetch its match words
        #pragma unroll
        for (int j = 0; j < 6; ++j) {
            int idx = tid + j * 512;
            if (idx < CV4_) r[j] = gbase[(size_t)c * CV4_ + idx];
        }
        int mkcur = match[c * CHA_ + tid];
        #pragma unroll
        for (int j = 0; j < 6; ++j) {
            int idx = tid + j * 512;
            if (idx < CV4_) s_stage[0][idx] = r[j];
        }
        __syncthreads();

        int k = 0;
        for (; c < NCH_; c += GRID_, ++k) {
            const int cn = c + GRID_;
            const bool hasnext = cn < NCH_;
            int mknext = 0;
            if (hasnext) {
                #pragma unroll
                for (int j = 0; j < 6; ++j) {
                    int idx = tid + j * 512;
                    if (idx < CV4_) r[j] = gbase[(size_t)cn * CV4_ + idx];
                }
                mknext = match[cn * CHA_ + tid];
            }

            // ---- compute chunk c from buf[k&1] ----
            const float* sc = (const float*)&s_stage[k & 1][0] + tid * C_;
            float m = sc[0];
            #pragma unroll
            for (int cc = 1; cc < C_; ++cc) m = fmaxf(m, sc[cc]);
            float s = 0.f;
            #pragma unroll
            for (int cc = 0; cc < C_; ++cc) s += __expf(sc[cc] - m);
            float lse = m + __logf(s);

            const int i    = c * CHA_ + tid;
            const int conf = mkcur & 0xff;
            const int g    = mkcur >> 8;
            float xc  = sc[conf];                 // single dynamic LDS read
            float nll = lse - xc;
            bool  pos = conf > 0;
            aux[i] = pos ? 0.f : nll;

            if (pos) {
                pnll += nll;
                int b = i / A_;                   // magic-mul const div
                int a = i - b * A_;
                float4 an = ((const float4*)anchors)[a];
                float4 bx = ((const float4*)tboxes)[b * G_ + g];
                float gcx = (bx.x + bx.z) * 0.5f, gcy = (bx.y + bx.w) * 0.5f;
                float gw = bx.z - bx.x, gh = bx.w - bx.y;
                float l0 = (gcx - an.x) / (an.z * VAR0_);
                float l1 = (gcy - an.y) / (an.w * VAR0_);
                float l2 = logf(gw / an.z) / VAR1_;
                float l3 = logf(gh / an.w) / VAR1_;
                float4 p = ((const float4*)pred_off)[i];
                float d, ad;
                d = p.x - l0; ad = fabsf(d); lloc += (ad < 1.f) ? 0.5f * d * d : ad - 0.5f;
                d = p.y - l1; ad = fabsf(d); lloc += (ad < 1.f) ? 0.5f * d * d : ad - 0.5f;
                d = p.z - l2; ad = fabsf(d); lloc += (ad < 1.f) ? 0.5f * d * d : ad - 0.5f;
                d = p.w - l3; ad = fabsf(d); lloc += (ad < 1.f) ? 0.5f * d * d : ad - 0.5f;
            }

            __syncthreads();                      // everyone done with buf[k&1]
            if (hasnext) {
                #pragma unroll
                for (int j = 0; j < 6; ++j) {
                    int idx = tid + j * 512;
                    if (idx < CV4_) s_stage[(k + 1) & 1][idx] = r[j];
                }
                mkcur = mknext;
                __syncthreads();                  // next buffer ready
            }
        }

        #pragma unroll
        for (int off = 32; off > 0; off >>= 1) {
            lloc += __shfl_down(lloc, off);
            pnll += __shfl_down(pnll, off);
        }
        if (lane == 0) { s_r0[w] = lloc; s_r1[w] = pnll; }
        __syncthreads();
        if (tid == 0) {
            float L = 0.f, P = 0.f;
            #pragma unroll
            for (int wv = 0; wv < 8; ++wv) { L += s_r0[wv]; P += s_r1[wv]; }
            ploc_b[bid] = L;
            pcls_b[bid] = P;
        }
    }
    gridg.sync();

    // ================= Phase D: hard-negative mining (blocks 0..127) ======
    if (bid < B_) {
        const int b = bid;
        unsigned u[NPT_];
        #pragma unroll
        for (int j = 0; j < NPT_; ++j) {
            int a = tid + j * 512;
            u[j] = (a < A_) ? __float_as_uint(aux[(size_t)b * A_ + a]) : 0u;
        }

        const int K = min(NEG_POS_ * npos_b[b], A_ - 1);

        unsigned lo = 0u, hi = 0x7f800000u;
        int it = 0;
        while (lo < hi) {
            unsigned mid = (lo + hi) >> 1;
            int cx = 0;
            #pragma unroll
            for (int j = 0; j < NPT_; ++j) cx += (u[j] > mid);
            #pragma unroll
            for (int off = 32; off > 0; off >>= 1) cx += __shfl_down(cx, off);
            if (lane == 0) s_c[it & 1][w] = cx;
            __syncthreads();
            int total = 0;
            #pragma unroll
            for (int wv = 0; wv < 8; ++wv) total += s_c[it & 1][wv];
            if (total >= K) lo = mid + 1; else hi = mid;
            ++it;
        }
        // lo == bit pattern of T = K-th largest aux value

        int selc = 0; float selsm = 0.f;
        #pragma unroll
        for (int j = 0; j < NPT_; ++j) {
            if (u[j] > lo) { selc++; selsm += __uint_as_float(u[j]); }
        }
        #pragma unroll
        for (int off = 32; off > 0; off >>= 1) {
            selc  += __shfl_down(selc, off);
            selsm += __shfl_down(selsm, off);
        }
        if (lane == 0) { s_r2[w] = selc; s_r3[w] = selsm; }
        __syncthreads();
        if (tid == 0) {
            int ct = 0; float st = 0.f;
            #pragma unroll
            for (int wv = 0; wv < 8; ++wv) { ct += s_r2[wv]; st += s_r3[wv]; }
            float T = __uint_as_float(lo);
            scls_b[b] = st + (float)(K - ct) * T;
        }
    }
    gridg.sync();

    // ================= Phase E: final reduce (block 0) ====================
    if (bid == 0) {
        float L  = (tid < GRID_) ? ploc_b[tid] : 0.f;
        float Cc = (tid < GRID_) ? pcls_b[tid] : 0.f;
        if (tid < B_) Cc += scls_b[tid];
        float n  = (tid < B_) ? (float)npos_b[tid] : 0.f;
        #pragma unroll
        for (int off = 32; off > 0; off >>= 1) {
            L  += __shfl_down(L, off);
            Cc += __shfl_down(Cc, off);
            n  += __shfl_down(n, off);
        }
        if (lane == 0) { s_r0[w] = L; s_r1[w] = Cc; s_r3[w] = n; }
        __syncthreads();
        if (tid == 0) {
            float Lt = 0.f, Ct = 0.f, Nt = 0.f;
            #pragma unroll
            for (int wv = 0; wv < 8; ++wv) { Lt += s_r0[wv]; Ct += s_r1[wv]; Nt += s_r3[wv]; }
            out[0] = Lt / Nt;
            out[1] = Ct / Nt;
        }
    }
}

// ---------------------------------------------------------------------------
extern "C" void kernel_launch(void* const* d_in, const int* in_sizes, int n_in,
                              void* d_out, int out_size, void* d_ws, size_t ws_size,
                              hipStream_t stream) {
    const float* pred_off  = (const float*)d_in[0];  // B,A,4
    const float* pred_conf = (const float*)d_in[1];  // B,A,C
    const float* tboxes    = (const float*)d_in[2];  // B,G,4
    const int*   tlabels   = (const int*)  d_in[3];  // B,G
    const float* anchors   = (const float*)d_in[4];  // A,4
    float* out = (float*)d_out;

    // workspace layout (16B-aligned pieces; every word fully rewritten
    // each iteration -> re-poison safe)
    char* ws = (char*)d_ws;
    int*   match_ws = (int*)ws;   ws += (size_t)BA_ * sizeof(int);
    float* aux_ws   = (float*)ws; ws += (size_t)BA_ * sizeof(float);
    float* ploc_ws  = (float*)ws; ws += (size_t)GRID_ * sizeof(float);
    float* pcls_ws  = (float*)ws; ws += (size_t)GRID_ * sizeof(float);
    float* scls_ws  = (float*)ws; ws += (size_t)B_ * sizeof(float);
    int*   npos_ws  = (int*)ws;

    void* args[] = {
        (void*)&pred_off, (void*)&pred_conf, (void*)&tboxes,
        (void*)&tlabels,  (void*)&anchors,
        (void*)&match_ws, (void*)&aux_ws, (void*)&npos_ws,
        (void*)&ploc_ws,  (void*)&pcls_ws, (void*)&scls_ws,
        (void*)&out
    };
    hipLaunchCooperativeKernel((void*)k_all, dim3(GRID_), dim3(512),
                               args, 0, stream);
}